// Round 5
// baseline (251.771 us; speedup 1.0000x reference)
//
#include <hip/hip_runtime.h>

// Problem constants
#define NODES  116
#define HEADS  2
#define DH     116
#define HID    256
#define NGRAPH 512
#define NN     (NGRAPH*NODES)    // 59392
#define DEG    8
#define DOUT   (HEADS*DH)        // 232
#define RSTR   136               // parked-tile row stride (272B, 16B-aligned rows)

typedef short  s8v  __attribute__((ext_vector_type(8)));
typedef float  f4v  __attribute__((ext_vector_type(4)));

static __device__ __forceinline__ float bf2f(unsigned short u) {
    union { unsigned int i; float f; } c; c.i = ((unsigned int)u) << 16; return c.f;
}
static __device__ __forceinline__ unsigned short f2bf(float f) {
    union { float f; unsigned int u; } c; c.f = f;
    unsigned int u = c.u;
    unsigned int r = (u + 0x7FFFu + ((u >> 16) & 1u)) >> 16;   // RNE
    return (unsigned short)r;
}

#define GLD_LDS16(gptr, lptr) \
    __builtin_amdgcn_global_load_lds((const __attribute__((address_space(1))) void*)(gptr), \
                                     (__attribute__((address_space(3))) void*)(lptr), 16, 0, 0)

// ---------------------------------------------------------------------------
// P: wt bf16 [hd(2)][chunk(4)][kb(8)][quad(4)][n(128)][8k]; chunk = Wq,Wk,Wv,Ws
// columns hd*116..+116, transposed, zero-padded n>=116.  (round-0 verified)
// ---------------------------------------------------------------------------
__global__ __launch_bounds__(256) void prep_w(const float* __restrict__ Wq,
                                              const float* __restrict__ Wk,
                                              const float* __restrict__ Wv,
                                              const float* __restrict__ Ws,
                                              unsigned short* __restrict__ wt)
{
    unsigned int f = blockIdx.x * 256 + threadIdx.x;   // granule id < 32768
    unsigned int n    = f & 127;
    unsigned int quad = (f >> 7) & 3;
    unsigned int kb   = (f >> 9) & 7;
    unsigned int ch   = (f >> 12) & 3;
    unsigned int hd   = f >> 14;
    unsigned short o[8] = {0,0,0,0,0,0,0,0};
    if (n < NODES) {
        unsigned int col = hd * DH + n;
        unsigned int k   = kb * 32 + quad * 8;
        const float* W = (ch == 0) ? Wq : (ch == 1) ? Wk : (ch == 2) ? Wv : Ws;
        #pragma unroll
        for (int i = 0; i < 8; i++)
            o[i] = f2bf(W[(size_t)(k + i) * DOUT + col]);
    }
    *(uint4*)(wt + (size_t)f * 8) = *(const uint4*)o;
}

// ---------------------------------------------------------------------------
// K1: per-(graph,head) chunk-OUTER GEMM. 1024 thr = 16 waves (4x4 over 128x128).
//   Only ONE chunk's acc (16 f32) live -> fits 64-VGPR budget at 32 waves/CU.
//   LDS: compact A [kb(8)][quad(4)][row(116)][8k] 59.6KB + B-dbuf 16KB = 76KB
//   -> 2 blocks/CU. t = ch*8+kb walks wt linearly; dbuf pipelined (R4-verified
//   stage-before-compute, one __syncthreads per step).
//   Writes q,k,v,s bf16 to qkvs[node][hd][ch(4)][116].
// ---------------------------------------------------------------------------
__global__ __launch_bounds__(1024, 8) void k1_gemm(
    const float* __restrict__ h,
    const unsigned short* __restrict__ wt,
    unsigned short* __restrict__ qkvs)
{
    __shared__ __align__(16) unsigned short stA[8*4*116*8 + 96];  // 59,584 B (+pad for row>=116 reads)
    __shared__ __align__(16) unsigned short stB[2*4096];          // 16,384 B dbuf [quad][n128][8k]
    // total 75,968 B -> 2 blocks/CU

    const int b   = blockIdx.x;
    const int g   = b >> 1;
    const int hd  = b & 1;
    const int tid = threadIdx.x;
    const int w    = tid >> 6;
    const int lane = tid & 63;
    const int l15  = lane & 15;
    const int quad = lane >> 4;
    const int wm   = w >> 2;
    const int wn   = w & 3;

    // ---- A-fill: h f32 -> bf16 -> compact stA (rows 0..115 only) ----
    {
        const int am = tid >> 3;          // 0..127
        const int q8 = tid & 7;
        if (am < NODES) {
            const float* hrow = h + ((size_t)g * NODES + am) * HID + q8 * 4;
            #pragma unroll
            for (int kb = 0; kb < 8; kb++) {
                float4 av = *(const float4*)(hrow + kb * 32);
                unsigned short o[4] = { f2bf(av.x), f2bf(av.y), f2bf(av.z), f2bf(av.w) };
                *(uint2*)(stA + kb * (4*116*8) + ((q8 >> 1) * 116 + am) * 8 + (q8 & 1) * 4) =
                    *(const uint2*)o;
            }
        }
    }

    const size_t wbase = (size_t)hd * 4 * 8 * 4096;   // els

    // ---- prologue: stage t=0 (ch0,kb0) into buf0 (waves 0..7, 1KB each) ----
    if (w < 8) {
        const unsigned short* src = wt + wbase + w * 512;
        GLD_LDS16((const char*)src + lane * 16, (char*)stB + w * 1024);
    }
    __syncthreads();

    f4v acc[2][2];
    #pragma unroll
    for (int i = 0; i < 2; i++)
        #pragma unroll
        for (int j = 0; j < 2; j++)
            #pragma unroll
            for (int r = 0; r < 4; r++) acc[i][j][r] = 0.f;

    for (int t = 0; t < 32; t++) {                    // t = ch*8 + kb
        const int kb = t & 7;
        const unsigned short* cur = stB + (t & 1) * 4096;
        if (t < 31 && w < 8) {
            const unsigned short* src = wt + wbase + (size_t)(t + 1) * 4096 + w * 512;
            GLD_LDS16((const char*)src + lane * 16,
                      (char*)stB + ((t & 1) ^ 1) * 8192 + w * 1024);
        }
        const unsigned short* sa = stA + kb * (4*116*8);
        s8v a0 = *(const s8v*)(sa + (quad * 116 + wm * 32 + l15) * 8);
        s8v a1 = *(const s8v*)(sa + (quad * 116 + wm * 32 + 16 + l15) * 8);
        s8v b0 = *(const s8v*)(cur + (quad * 128 + wn * 32 + l15) * 8);
        s8v b1 = *(const s8v*)(cur + (quad * 128 + wn * 32 + 16 + l15) * 8);
        acc[0][0] = __builtin_amdgcn_mfma_f32_16x16x32_bf16(a0, b0, acc[0][0], 0, 0, 0);
        acc[0][1] = __builtin_amdgcn_mfma_f32_16x16x32_bf16(a0, b1, acc[0][1], 0, 0, 0);
        acc[1][0] = __builtin_amdgcn_mfma_f32_16x16x32_bf16(a1, b0, acc[1][0], 0, 0, 0);
        acc[1][1] = __builtin_amdgcn_mfma_f32_16x16x32_bf16(a1, b1, acc[1][1], 0, 0, 0);
        if (kb == 7) {
            const int ch = t >> 3;
            #pragma unroll
            for (int i = 0; i < 2; i++) {
                #pragma unroll
                for (int j = 0; j < 2; j++) {
                    int col = wn * 32 + j * 16 + l15;
                    #pragma unroll
                    for (int r = 0; r < 4; r++) {
                        int row = wm * 32 + i * 16 + quad * 4 + r;
                        if (row < NODES && col < NODES)
                            qkvs[(((size_t)g * NODES + row) * 2 + hd) * 464 + ch * 116 + col] =
                                f2bf(acc[i][j][r]);
                        acc[i][j][r] = 0.f;
                    }
                }
            }
        }
        __syncthreads();
    }
}

// ---------------------------------------------------------------------------
// K2: per-(graph,head) MFMA attention (R4-verified phase code, sources from
//   qkvs).  LDS: ql + kl (34.8KB each) + srcl/scf = 77KB -> 2 blocks/CU.
//   park q,k (zero cols 116..127) -> QK^T -> scatter -> softmax -> zero-W +
//   V^T park (+zero vt rows>=116) -> W-build -> WV -> +s (LDS-staged) ->
//   h_proj park -> rowsums -> psums + hpj[node][232] bf16.
// ---------------------------------------------------------------------------
__global__ __launch_bounds__(1024, 8) void k2_attn(
    const unsigned short* __restrict__ qkvs,
    const int* __restrict__ eidx,
    unsigned short* __restrict__ hpj,
    float* __restrict__ psums)
{
    __shared__ __align__(16) unsigned short ql[128*RSTR];   // 34,816 B  q -> v^T -> h_proj
    __shared__ __align__(16) unsigned short kl[128*RSTR];   // 34,816 B  k -> dense W -> s
    __shared__ int   srcl[NODES*DEG];                       //  3,712 B
    __shared__ float scf[NODES*DEG];                        //  3,712 B
    // total 77,056 B -> 2 blocks/CU

    const int b   = blockIdx.x;
    const int g   = b >> 1;
    const int hd  = b & 1;
    const int tid = threadIdx.x;
    const int w    = tid >> 6;
    const int lane = tid & 63;
    const int l15  = lane & 15;
    const int quad = lane >> 4;
    const int wm   = w >> 2;
    const int wn   = w & 3;

    if (tid < NODES * DEG)
        srcl[tid] = eidx[(size_t)g * NODES * DEG + tid] - g * NODES;

    const size_t nb = ((size_t)g * NODES) * 2 + hd;   // row addr = (nb + r*2)*464

    // ---- park q,k from qkvs (coalesced uint2) ----
    for (int f = tid; f < NODES * 29; f += 1024) {
        int r = f / 29, c = f - r * 29;
        *(uint2*)(ql + r * RSTR + c * 4) =
            *(const uint2*)(qkvs + (nb + (size_t)r * 2) * 464 + 0 * 116 + c * 4);
        *(uint2*)(kl + r * RSTR + c * 4) =
            *(const uint2*)(qkvs + (nb + (size_t)r * 2) * 464 + 1 * 116 + c * 4);
    }
    // zero k-sweep pad cols 116..127, all 128 rows
    for (int f = tid; f < 128 * 3; f += 1024) {
        int r = f / 3, j = f - r * 3;
        *(uint2*)(ql + r * RSTR + 116 + j * 4) = make_uint2(0u, 0u);
        *(uint2*)(kl + r * RSTR + 116 + j * 4) = make_uint2(0u, 0u);
    }
    __syncthreads();

    // ---- S = Q.K^T (K=128) ----
    f4v sacc[2][2];
    #pragma unroll
    for (int i = 0; i < 2; i++)
        #pragma unroll
        for (int j = 0; j < 2; j++)
            #pragma unroll
            for (int r = 0; r < 4; r++) sacc[i][j][r] = 0.f;
    #pragma unroll
    for (int ks = 0; ks < 4; ks++) {
        s8v a0 = *(const s8v*)(ql + (wm * 32 + l15) * RSTR + ks * 32 + quad * 8);
        s8v a1 = *(const s8v*)(ql + (wm * 32 + 16 + l15) * RSTR + ks * 32 + quad * 8);
        s8v b0 = *(const s8v*)(kl + (wn * 32 + l15) * RSTR + ks * 32 + quad * 8);
        s8v b1 = *(const s8v*)(kl + (wn * 32 + 16 + l15) * RSTR + ks * 32 + quad * 8);
        sacc[0][0] = __builtin_amdgcn_mfma_f32_16x16x32_bf16(a0, b0, sacc[0][0], 0, 0, 0);
        sacc[0][1] = __builtin_amdgcn_mfma_f32_16x16x32_bf16(a0, b1, sacc[0][1], 0, 0, 0);
        sacc[1][0] = __builtin_amdgcn_mfma_f32_16x16x32_bf16(a1, b0, sacc[1][0], 0, 0, 0);
        sacc[1][1] = __builtin_amdgcn_mfma_f32_16x16x32_bf16(a1, b1, sacc[1][1], 0, 0, 0);
    }
    // selective scatter (verified form)
    #pragma unroll
    for (int i = 0; i < 2; i++) {
        #pragma unroll
        for (int r = 0; r < 4; r++) {
            int row = wm * 32 + i * 16 + quad * 4 + r;
            if (row < NODES) {
                #pragma unroll
                for (int j = 0; j < 2; j++) {
                    int col = wn * 32 + j * 16 + l15;
                    #pragma unroll
                    for (int e = 0; e < DEG; e++)
                        if (srcl[row * DEG + e] == col)
                            scf[row * DEG + e] = sacc[i][j][r];
                }
            }
        }
    }
    __syncthreads();     // scf ready; ql/kl MFMA reads done

    // ---- zero dense-W (kl) + V^T park into ql + zero vt rows 116..127 ----
    for (int f = tid; f < 128 * RSTR / 8; f += 1024)
        *(uint4*)(kl + (size_t)f * 8) = make_uint4(0u, 0u, 0u, 0u);
    for (int f = tid; f < NODES * 29; f += 1024) {
        int r = f / 29, c = f - r * 29;
        uint2 vv = *(const uint2*)(qkvs + (nb + (size_t)r * 2) * 464 + 2 * 116 + c * 4);
        const unsigned short* vp = (const unsigned short*)&vv;
        #pragma unroll
        for (int i = 0; i < 4; i++)
            ql[(c * 4 + i) * RSTR + r] = vp[i];     // vt[dim][src]
    }
    if (tid < 12 * 17) {
        int r = 116 + tid / 17, c = tid - (tid / 17) * 17;
        *(uint4*)(ql + r * RSTR + c * 8) = make_uint4(0u, 0u, 0u, 0u);
    }
    __syncthreads();

    // ---- softmax over 8 edges, in place in scf ----
    if (tid < NODES * DEG) {
        float s = scf[tid] * 0.09284766908852594f;   // 1/sqrt(116)
        float m = s;
        m = fmaxf(m, __shfl_xor(m, 1));
        m = fmaxf(m, __shfl_xor(m, 2));
        m = fmaxf(m, __shfl_xor(m, 4));
        float e = __expf(s - m);
        float sum = e;
        sum += __shfl_xor(sum, 1);
        sum += __shfl_xor(sum, 2);
        sum += __shfl_xor(sum, 4);
        scf[tid] = e / sum;
    }
    __syncthreads();

    // ---- build dense W[dst][src] bf16, duplicates folded in f32 ----
    if (tid < NODES) {
        #pragma unroll
        for (int j = 0; j < DEG; j++) {
            int sj = srcl[tid * DEG + j];
            bool first = true;
            for (int jj = 0; jj < j; jj++) first = first && (srcl[tid * DEG + jj] != sj);
            if (first) {
                float a = scf[tid * DEG + j];
                for (int jj = j + 1; jj < DEG; jj++)
                    if (srcl[tid * DEG + jj] == sj) a += scf[tid * DEG + jj];
                kl[tid * RSTR + sj] = f2bf(a);
            }
        }
    }
    __syncthreads();

    // ---- attn = W @ V (K=128) ----
    f4v accs[2][2];
    #pragma unroll
    for (int i = 0; i < 2; i++)
        #pragma unroll
        for (int j = 0; j < 2; j++)
            #pragma unroll
            for (int r = 0; r < 4; r++) accs[i][j][r] = 0.f;
    #pragma unroll
    for (int ks = 0; ks < 4; ks++) {
        s8v a0 = *(const s8v*)(kl + (wm * 32 + l15) * RSTR + ks * 32 + quad * 8);
        s8v a1 = *(const s8v*)(kl + (wm * 32 + 16 + l15) * RSTR + ks * 32 + quad * 8);
        s8v b0 = *(const s8v*)(ql + (wn * 32 + l15) * RSTR + ks * 32 + quad * 8);
        s8v b1 = *(const s8v*)(ql + (wn * 32 + 16 + l15) * RSTR + ks * 32 + quad * 8);
        accs[0][0] = __builtin_amdgcn_mfma_f32_16x16x32_bf16(a0, b0, accs[0][0], 0, 0, 0);
        accs[0][1] = __builtin_amdgcn_mfma_f32_16x16x32_bf16(a0, b1, accs[0][1], 0, 0, 0);
        accs[1][0] = __builtin_amdgcn_mfma_f32_16x16x32_bf16(a1, b0, accs[1][0], 0, 0, 0);
        accs[1][1] = __builtin_amdgcn_mfma_f32_16x16x32_bf16(a1, b1, accs[1][1], 0, 0, 0);
    }
    __syncthreads();     // kl (W) reads done -> reuse kl for s

    // ---- stage s rows into kl (coalesced) ----
    for (int f = tid; f < NODES * 29; f += 1024) {
        int r = f / 29, c = f - r * 29;
        *(uint2*)(kl + r * RSTR + c * 4) =
            *(const uint2*)(qkvs + (nb + (size_t)r * 2) * 464 + 3 * 116 + c * 4);
    }
    __syncthreads();

    // ---- h_proj = attn + s -> park into ql ----
    #pragma unroll
    for (int i = 0; i < 2; i++) {
        #pragma unroll
        for (int j = 0; j < 2; j++) {
            int col = wn * 32 + j * 16 + l15;
            #pragma unroll
            for (int r = 0; r < 4; r++) {
                int row = wm * 32 + i * 16 + quad * 4 + r;
                float v = accs[i][j][r];
                if (row < NODES && col < NODES) v += bf2f(kl[row * RSTR + col]);
                ql[row * RSTR + col] = f2bf(v);
            }
        }
    }
    __syncthreads();

    // ---- row partial sums -> psums ----
    if (tid < NODES * DEG) {
        const int i   = tid >> 3;
        const int seg = tid & 7;
        float rs = 0.0f;
        #pragma unroll
        for (int t = 0; t < 2; t++) {
            int gi = seg + t * 8;
            if (gi < 15) {                       // cols 116..127 are exact zeros
                const s8v v8 = *(const s8v*)(ql + i * RSTR + gi * 8);
                #pragma unroll
                for (int e = 0; e < 8; e++) rs += bf2f((unsigned short)v8[e]);
            }
        }
        rs += __shfl_xor(rs, 1);
        rs += __shfl_xor(rs, 2);
        rs += __shfl_xor(rs, 4);
        if (seg == 0) psums[((size_t)hd * NGRAPH + g) * NODES + i] = rs;
    }
    // ---- hpj[node][232] bf16 (head halves) ----
    for (int f = tid; f < NODES * 29; f += 1024) {
        int r  = f / 29;
        int gi = f - r * 29;
        *(uint2*)(hpj + ((size_t)(g * NODES + r)) * DOUT + hd * DH + gi * 4) =
            *(const uint2*)(ql + r * RSTR + gi * 4);
    }
}

// ---------------------------------------------------------------------------
// K3: per-graph pooling (round-0 verified pool_k2, verbatim layouts).
// ---------------------------------------------------------------------------
__global__ __launch_bounds__(256) void pool_k3(const unsigned short* __restrict__ hp,
                                               const float* __restrict__ psums,
                                               float* __restrict__ out_alpha,
                                               float* __restrict__ out_hw)
{
    __shared__ float ew[NODES];
    __shared__ float alph[NODES];
    __shared__ float red[2];

    const int g   = blockIdx.x;
    const int tid = threadIdx.x;

    if (tid < NODES)
        ew[tid] = (psums[(size_t)g * NODES + tid] +
                   psums[((size_t)NGRAPH + g) * NODES + tid]) * (1.0f / DOUT);
    __syncthreads();
    if (tid < 64) {
        float a = ew[tid];
        float b = (tid + 64 < NODES) ? ew[tid + 64] : -1e30f;
        float mm = fmaxf(a, b);
        #pragma unroll
        for (int off = 32; off > 0; off >>= 1) mm = fmaxf(mm, __shfl_down(mm, off));
        if (tid == 0) red[0] = mm;
    }
    __syncthreads();
    if (tid < NODES) ew[tid] = __expf(ew[tid] - red[0]);
    __syncthreads();
    if (tid < 64) {
        float a = ew[tid] + ((tid + 64 < NODES) ? ew[tid + 64] : 0.0f);
        #pragma unroll
        for (int off = 32; off > 0; off >>= 1) a += __shfl_down(a, off);
        if (tid == 0) red[1] = a;
    }
    __syncthreads();
    if (tid < NODES) {
        float al = ew[tid] / red[1];
        alph[tid] = al;
        out_alpha[(size_t)g * NODES + tid] = al;
    }
    __syncthreads();

    for (int f = tid; f < NODES * 58; f += 256) {   // 58 4-el granules per row
        int r  = f / 58;
        int gi = f - r * 58;
        float al = alph[r];
        uint2 hv = *(const uint2*)(hp + ((size_t)(g * NODES + r)) * DOUT + gi * 4);
        float4 o = make_float4(al * bf2f((unsigned short)(hv.x & 0xFFFF)),
                               al * bf2f((unsigned short)(hv.x >> 16)),
                               al * bf2f((unsigned short)(hv.y & 0xFFFF)),
                               al * bf2f((unsigned short)(hv.y >> 16)));
        *(float4*)(out_hw + ((size_t)(g * NODES + r)) * DOUT + gi * 4) = o;
    }
}

// ===========================================================================
// FALLBACK (ws too small): round-4 verified monolith, unchanged.
// ===========================================================================
__global__ __launch_bounds__(1024, 4) void fused_all(
    const float* __restrict__ h,
    const unsigned short* __restrict__ wt,
    const int* __restrict__ eidx,
    unsigned short* __restrict__ hp,
    float* __restrict__ out_alpha,
    float* __restrict__ out_hw)
{
    __shared__ __align__(16) unsigned short stA[8*4096];
    __shared__ __align__(16) unsigned short ovl[2*128*RSTR];
    __shared__ int   srcl[NODES*DEG];
    __shared__ float scf[NODES*DEG];
    __shared__ float ps[2][NODES];
    __shared__ float red[2];

    unsigned short* const ql = ovl;
    unsigned short* const kl = ovl + 128 * RSTR;

    const int g   = blockIdx.x;
    const int tid = threadIdx.x;
    const int w    = tid >> 6;
    const int lane = tid & 63;
    const int l15  = lane & 15;
    const int quad = lane >> 4;
    const int wm   = w >> 2;
    const int wn   = w & 3;

    if (tid < NODES * DEG)
        srcl[tid] = eidx[(size_t)g * NODES * DEG + tid] - g * NODES;

    {
        const int am = tid >> 3;
        const int q8 = tid & 7;
        long grow = (long)g * NODES + am;
        if (grow >= NN) grow = NN - 1;
        const float* hrow = h + (size_t)grow * HID + q8 * 4;
        const int aoff = ((q8 >> 1) * 128 + am) * 8 + (q8 & 1) * 4;
        float4 a8[8];
        #pragma unroll
        for (int kb = 0; kb < 8; kb++) a8[kb] = *(const float4*)(hrow + kb * 32);
        #pragma unroll
        for (int kb = 0; kb < 8; kb++) {
            unsigned short o[4] = { f2bf(a8[kb].x), f2bf(a8[kb].y),
                                    f2bf(a8[kb].z), f2bf(a8[kb].w) };
            *(uint2*)(stA + kb * 4096 + aoff) = *(const uint2*)o;
        }
    }

    #pragma unroll
    for (int hd = 0; hd < 2; hd++) {
        const size_t wbase = (size_t)hd * 4 * 8 * 4096;

        f4v accq[2][2], acck[2][2], accv[2][2], accs[2][2];
        #pragma unroll
        for (int i = 0; i < 2; i++)
            #pragma unroll
            for (int j = 0; j < 2; j++)
                #pragma unroll
                for (int r = 0; r < 4; r++) {
                    accq[i][j][r] = 0.f; acck[i][j][r] = 0.f;
                    accv[i][j][r] = 0.f; accs[i][j][r] = 0.f;
                }

        #pragma unroll
        for (int j = 0; j < 2; j++) {
            int c = w * 2 + j;
            int ch = c >> 3, sub = c & 7;
            const unsigned short* src = wt + wbase + ((size_t)(ch * 8)) * 4096 + sub * 512;
            GLD_LDS16((const char*)src + lane * 16, (char*)ovl + c * 1024);
        }
        __syncthreads();

        #pragma unroll
        for (int kb = 0; kb < 8; kb++) {
            const unsigned short* curb = ovl + (kb & 1) * 16384;
            unsigned short* nxtb = ovl + ((kb & 1) ^ 1) * 16384;
            if (kb < 7) {
                #pragma unroll
                for (int j = 0; j < 2; j++) {
                    int c = w * 2 + j;
                    int ch = c >> 3, sub = c & 7;
                    const unsigned short* src = wt + wbase + ((size_t)(ch * 8 + kb + 1)) * 4096 + sub * 512;
                    GLD_LDS16((const char*)src + lane * 16, (char*)nxtb + c * 1024);
                }
            }
            const unsigned short* sa = stA + kb * 4096;
            s8v a0 = *(const s8v*)(sa + (quad * 128 + wm * 32 + l15) * 8);
            s8v a1 = *(const s8v*)(sa + (quad * 128 + wm * 32 + 16 + l15) * 8);
            #define CHUNK_MFMA(ACC, CH) { \
                s8v b0 = *(const s8v*)(curb + (CH) * 4096 + (quad * 128 + wn * 32 + l15) * 8); \
                s8v b1 = *(const s8v*)(curb + (CH) * 4096 + (quad * 128 + wn * 32 + 16 + l15) * 8); \
                ACC[0][0] = __builtin_amdgcn_mfma_f32_16x16x32_bf16(a0, b0, ACC[0][0], 0, 0, 0); \
                ACC[0][1] = __builtin_amdgcn_mfma_f32_16x16x32_bf16(a0, b1, ACC[0][1], 0, 0, 0); \
                ACC[1][0] = __builtin_amdgcn_mfma_f32_16x16x32_bf16(a1, b0, ACC[1][0], 0, 0, 0); \
                ACC[1][1] = __builtin_amdgcn_mfma_f32_16x16x32_bf16(a1, b1, ACC[1][1], 0, 0, 0); }
            CHUNK_MFMA(accq, 0)
            CHUNK_MFMA(acck, 1)
            CHUNK_MFMA(accv, 2)
            CHUNK_MFMA(accs, 3)
            #undef CHUNK_MFMA
            __syncthreads();
        }

        #pragma unroll
        for (int i = 0; i < 2; i++) {
            #pragma unroll
            for (int j = 0; j < 2; j++) {
                int col = wn * 32 + j * 16 + l15;
                #pragma unroll
                for (int r = 0; r < 4; r++) {
                    int row = wm * 32 + i * 16 + quad * 4 + r;
                    ql[row * RSTR + col] = (col < NODES) ? f2bf(accq[i][j][r]) : 0;
                    kl[row * RSTR + col] = (col < NODES) ? f2bf(acck[i][j][r]) : 0;
                }
            }
        }
        __syncthreads();

        f4v sacc[2][2];
        #pragma unroll
        for (int i = 0; i < 2; i++)
            #pragma unroll
            for (int j = 0; j < 2; j++)
                #pragma unroll
                for (int r = 0; r < 4; r++) sacc[i][j][r] = 0.f;
        #pragma unroll
        for (int ks = 0; ks < 4; ks++) {
            s8v a0 = *(const s8v*)(ql + (wm * 32 + l15) * RSTR + ks * 32 + quad * 8);
            s8v a1 = *(const s8v*)(ql + (wm * 32 + 16 + l15) * RSTR + ks * 32 + quad * 8);
            s8v b0 = *(const s8v*)(kl + (wn * 32 + l15) * RSTR + ks * 32 + quad * 8);
            s8v b1 = *(const s8v*)(kl + (wn * 32 + 16 + l15) * RSTR + ks * 32 + quad * 8);
            sacc[0][0] = __builtin_amdgcn_mfma_f32_16x16x32_bf16(a0, b0, sacc[0][0], 0, 0, 0);
            sacc[0][1] = __builtin_amdgcn_mfma_f32_16x16x32_bf16(a0, b1, sacc[0][1], 0, 0, 0);
            sacc[1][0] = __builtin_amdgcn_mfma_f32_16x16x32_bf16(a1, b0, sacc[1][0], 0, 0, 0);
            sacc[1][1] = __builtin_amdgcn_mfma_f32_16x16x32_bf16(a1, b1, sacc[1][1], 0, 0, 0);
        }
        #pragma unroll
        for (int i = 0; i < 2; i++) {
            #pragma unroll
            for (int r = 0; r < 4; r++) {
                int row = wm * 32 + i * 16 + quad * 4 + r;
                if (row < NODES) {
                    #pragma unroll
                    for (int j = 0; j < 2; j++) {
                        int col = wn * 32 + j * 16 + l15;
                        #pragma unroll
                        for (int e = 0; e < DEG; e++)
                            if (srcl[row * DEG + e] == col)
                                scf[row * DEG + e] = sacc[i][j][r];
                    }
                }
            }
        }
        __syncthreads();

        for (int f = tid; f < 128 * RSTR / 8; f += 1024)
            *(uint4*)(kl + (size_t)f * 8) = make_uint4(0u, 0u, 0u, 0u);
        #pragma unroll
        for (int i = 0; i < 2; i++) {
            #pragma unroll
            for (int j = 0; j < 2; j++) {
                int col = wn * 32 + j * 16 + l15;
                #pragma unroll
                for (int r = 0; r < 4; r++) {
                    int row = wm * 32 + i * 16 + quad * 4 + r;
                    ql[col * RSTR + row] = (row < NODES) ? f2bf(accv[i][j][r]) : 0;
                }
            }
        }
        __syncthreads();

        if (tid < NODES * DEG) {
            float s = scf[tid] * 0.09284766908852594f;
            float m = s;
            m = fmaxf(m, __shfl_xor(m, 1));
            m = fmaxf(m, __shfl_xor(m, 2));
            m = fmaxf(m, __shfl_xor(m, 4));
            float e = __expf(s - m);
            float sum = e;
            sum += __shfl_xor(sum, 1);
            sum += __shfl_xor(sum, 2);
            sum += __shfl_xor(sum, 4);
            scf[tid] = e / sum;
        }
        __syncthreads();

        if (tid < NODES) {
            #pragma unroll
            for (int j = 0; j < DEG; j++) {
                int sj = srcl[tid * DEG + j];
                bool first = true;
                for (int jj = 0; jj < j; jj++) first = first && (srcl[tid * DEG + jj] != sj);
                if (first) {
                    float a = scf[tid * DEG + j];
                    for (int jj = j + 1; jj < DEG; jj++)
                        if (srcl[tid * DEG + jj] == sj) a += scf[tid * DEG + jj];
                    kl[tid * RSTR + sj] = f2bf(a);
                }
            }
        }
        __syncthreads();

        #pragma unroll
        for (int ks = 0; ks < 4; ks++) {
            s8v a0 = *(const s8v*)(kl + (wm * 32 + l15) * RSTR + ks * 32 + quad * 8);
            s8v a1 = *(const s8v*)(kl + (wm * 32 + 16 + l15) * RSTR + ks * 32 + quad * 8);
            s8v b0 = *(const s8v*)(ql + (wn * 32 + l15) * RSTR + ks * 32 + quad * 8);
            s8v b1 = *(const s8v*)(ql + (wn * 32 + 16 + l15) * RSTR + ks * 32 + quad * 8);
            accs[0][0] = __builtin_amdgcn_mfma_f32_16x16x32_bf16(a0, b0, accs[0][0], 0, 0, 0);
            accs[0][1] = __builtin_amdgcn_mfma_f32_16x16x32_bf16(a0, b1, accs[0][1], 0, 0, 0);
            accs[1][0] = __builtin_amdgcn_mfma_f32_16x16x32_bf16(a1, b0, accs[1][0], 0, 0, 0);
            accs[1][1] = __builtin_amdgcn_mfma_f32_16x16x32_bf16(a1, b1, accs[1][1], 0, 0, 0);
        }
        __syncthreads();

        #pragma unroll
        for (int i = 0; i < 2; i++) {
            #pragma unroll
            for (int j = 0; j < 2; j++) {
                int col = wn * 32 + j * 16 + l15;
                #pragma unroll
                for (int r = 0; r < 4; r++) {
                    int row = wm * 32 + i * 16 + quad * 4 + r;
                    ql[row * RSTR + col] = f2bf(accs[i][j][r]);
                }
            }
        }
        __syncthreads();

        if (tid < NODES * DEG) {
            const int i   = tid >> 3;
            const int seg = tid & 7;
            float rs = 0.0f;
            #pragma unroll
            for (int t = 0; t < 2; t++) {
                int gi = seg + t * 8;
                if (gi < 15) {
                    const s8v v8 = *(const s8v*)(ql + i * RSTR + gi * 8);
                    #pragma unroll
                    for (int e = 0; e < 8; e++) rs += bf2f((unsigned short)v8[e]);
                }
            }
            rs += __shfl_xor(rs, 1);
            rs += __shfl_xor(rs, 2);
            rs += __shfl_xor(rs, 4);
            if (seg == 0) ps[hd][i] = rs;
        }
        if (hd == 0) {
            for (int f = tid; f < NODES * 29; f += 1024) {
                int r  = f / 29;
                int gi = f - r * 29;
                *(uint2*)(hp + ((size_t)g * NODES + r) * 116 + gi * 4) =
                    *(const uint2*)(ql + r * RSTR + gi * 4);
            }
        }
        __syncthreads();
    }

    if (tid < NODES) scf[tid] = (ps[0][tid] + ps[1][tid]) * (1.0f / DOUT);
    __syncthreads();
    if (tid < 64) {
        float a = scf[tid];
        float b = (tid + 64 < NODES) ? scf[tid + 64] : -1e30f;
        float mm = fmaxf(a, b);
        #pragma unroll
        for (int off = 32; off > 0; off >>= 1) mm = fmaxf(mm, __shfl_down(mm, off));
        if (tid == 0) red[0] = mm;
    }
    __syncthreads();
    if (tid < NODES) scf[tid] = __expf(scf[tid] - red[0]);
    __syncthreads();
    if (tid < 64) {
        float a = scf[tid] + ((tid + 64 < NODES) ? scf[tid + 64] : 0.0f);
        #pragma unroll
        for (int off = 32; off > 0; off >>= 1) a += __shfl_down(a, off);
        if (tid == 0) red[1] = a;
    }
    __syncthreads();
    if (tid < NODES) {
        float al = scf[tid] / red[1];
        scf[tid] = al;
        out_alpha[(size_t)g * NODES + tid] = al;
    }
    __syncthreads();
    for (int f = tid; f < NODES * 58; f += 1024) {
        int r  = f / 58;
        int gi = f - r * 58;
        float al = scf[r];
        float4 o;
        if (gi < 29) {
            uint2 hv = *(const uint2*)(hp + ((size_t)g * NODES + r) * 116 + gi * 4);
            o = make_float4(al * bf2f((unsigned short)(hv.x & 0xFFFF)),
                            al * bf2f((unsigned short)(hv.x >> 16)),
                            al * bf2f((unsigned short)(hv.y & 0xFFFF)),
                            al * bf2f((unsigned short)(hv.y >> 16)));
        } else {
            const unsigned short* hv = ql + r * RSTR + (gi - 29) * 4;
            o = make_float4(al * bf2f(hv[0]), al * bf2f(hv[1]),
                            al * bf2f(hv[2]), al * bf2f(hv[3]));
        }
        *(float4*)(out_hw + ((size_t)g * NODES + r) * DOUT + gi * 4) = o;
    }
}

// ---------------------------------------------------------------------------
extern "C" void kernel_launch(void* const* d_in, const int* in_sizes, int n_in,
                              void* d_out, int out_size, void* d_ws, size_t ws_size,
                              hipStream_t stream)
{
    const float* h    = (const float*)d_in[0];
    const int*   eidx = (const int*)d_in[1];   // row 0 = src
    const float* Wq   = (const float*)d_in[3];
    const float* Wk   = (const float*)d_in[4];
    const float* Wv   = (const float*)d_in[5];
    const float* Ws   = (const float*)d_in[6];

    float* out_alpha = (float*)d_out;          // [512][116]
    float* out_hw    = out_alpha + NN;         // [59392][232]

    // Split-path workspace: wt 0.5MB | qkvs 110.2MB | hpj 27.6MB | psums 0.5MB
    const size_t WT_ELS   = 262144;
    const size_t QKVS_ELS = (size_t)NN * 2 * 464;       // 55,115,776
    const size_t HPJ_ELS  = (size_t)NN * DOUT;          // 13,778,944
    const size_t NEED = (WT_ELS + QKVS_ELS + HPJ_ELS) * 2 + (size_t)2 * NGRAPH * NODES * 4;

    unsigned short* wt = (unsigned short*)d_ws;
    prep_w<<<128, 256, 0, stream>>>(Wq, Wk, Wv, Ws, wt);

    if (ws_size >= NEED) {
        unsigned short* qkvs = wt + WT_ELS;
        unsigned short* hpj  = qkvs + QKVS_ELS;
        float*          ps   = (float*)(hpj + HPJ_ELS);
        k1_gemm<<<2*NGRAPH, 1024, 0, stream>>>(h, wt, qkvs);
        k2_attn<<<2*NGRAPH, 1024, 0, stream>>>(qkvs, eidx, hpj, ps);
        pool_k3<<<NGRAPH, 256, 0, stream>>>(hpj, ps, out_alpha, out_hw);
    } else {
        unsigned short* hp = wt + WT_ELS;               // 13.8 MB (head0 only)
        fused_all<<<NGRAPH, 1024, 0, stream>>>(h, wt, eidx, hp, out_alpha, out_hw);
    }
}

// Round 6
// 237.456 us; speedup vs baseline: 1.0603x; 1.0603x over previous
//
#include <hip/hip_runtime.h>

// Problem constants
#define NODES  116
#define HEADS  2
#define DH     116
#define HID    256
#define NGRAPH 512
#define NN     (NGRAPH*NODES)    // 59392
#define DEG    8
#define DOUT   (HEADS*DH)        // 232
#define RSTR   136               // parked-tile row stride (272B, 16B-aligned rows)

typedef short  s8v  __attribute__((ext_vector_type(8)));
typedef float  f4v  __attribute__((ext_vector_type(4)));

static __device__ __forceinline__ float bf2f(unsigned short u) {
    union { unsigned int i; float f; } c; c.i = ((unsigned int)u) << 16; return c.f;
}
static __device__ __forceinline__ unsigned short f2bf(float f) {
    union { float f; unsigned int u; } c; c.f = f;
    unsigned int u = c.u;
    unsigned int r = (u + 0x7FFFu + ((u >> 16) & 1u)) >> 16;   // RNE
    return (unsigned short)r;
}

#define GLD_LDS16(gptr, lptr) \
    __builtin_amdgcn_global_load_lds((const __attribute__((address_space(1))) void*)(gptr), \
                                     (__attribute__((address_space(3))) void*)(lptr), 16, 0, 0)

// ---------------------------------------------------------------------------
// P: wt bf16 [hd(2)][chunk(4)][kb(8)][quad(4)][n(128)][8k]; chunk = Wq,Wk,Wv,Ws
// columns hd*116..+116, transposed, zero-padded n>=116.  (round-0 verified)
// ---------------------------------------------------------------------------
__global__ __launch_bounds__(256) void prep_w(const float* __restrict__ Wq,
                                              const float* __restrict__ Wk,
                                              const float* __restrict__ Wv,
                                              const float* __restrict__ Ws,
                                              unsigned short* __restrict__ wt)
{
    unsigned int f = blockIdx.x * 256 + threadIdx.x;   // granule id < 32768
    unsigned int n    = f & 127;
    unsigned int quad = (f >> 7) & 3;
    unsigned int kb   = (f >> 9) & 7;
    unsigned int ch   = (f >> 12) & 3;
    unsigned int hd   = f >> 14;
    unsigned short o[8] = {0,0,0,0,0,0,0,0};
    if (n < NODES) {
        unsigned int col = hd * DH + n;
        unsigned int k   = kb * 32 + quad * 8;
        const float* W = (ch == 0) ? Wq : (ch == 1) ? Wk : (ch == 2) ? Wv : Ws;
        #pragma unroll
        for (int i = 0; i < 8; i++)
            o[i] = f2bf(W[(size_t)(k + i) * DOUT + col]);
    }
    *(uint4*)(wt + (size_t)f * 8) = *(const uint4*)o;
}

// ---------------------------------------------------------------------------
// P2: hb = bf16(h), row-major [NN][256].  8 els/thread, coalesced.
// ---------------------------------------------------------------------------
__global__ __launch_bounds__(256) void prep_hb(const float* __restrict__ h,
                                               unsigned short* __restrict__ hb)
{
    size_t i = ((size_t)blockIdx.x * 256 + threadIdx.x) * 8;
    float4 a = *(const float4*)(h + i);
    float4 b = *(const float4*)(h + i + 4);
    unsigned short o[8] = { f2bf(a.x), f2bf(a.y), f2bf(a.z), f2bf(a.w),
                            f2bf(b.x), f2bf(b.y), f2bf(b.z), f2bf(b.w) };
    *(uint4*)(hb + i) = *(const uint4*)o;
}

// ---------------------------------------------------------------------------
// K_FUSED: per-(graph,head), 512 threads = 8 waves (4wm x 2wn; wave tile
//   32 rows x 64 cols; frags acc[i(2)][j(4)], 32 f32).
//   GEMM reads A (hb) and B (wt) DIRECTLY from global (L2-resident) — no LDS
//   staging, no barriers inside the GEMM.  Chunk order:
//     q -> park ql | k -> park kl | S1 | QK^T + scatter | S2 |
//     softmax + zero-kl | S3 | W-build (waves 0-1; others run ahead) |
//     v -> park vt into ql-region | S4 | s (held in regs) + WV + add | S5 |
//     h_proj park -> ql | S6 | rowsums -> psums, hpj write.
//   Only 2 LDS park tiles (q-region reused as vt then h_proj; k-region as W).
//   LDS = 75,216 B -> 2 blocks/CU; 512thr x 2 blocks = 4 waves/SIMD -> 128
//   VGPR budget (holds accS 32 + accW 32).
//   Arithmetic (K-order, frag maps, rounding) identical to round-4 verified.
// ---------------------------------------------------------------------------
__global__ __launch_bounds__(512, 4) void k_fused(
    const unsigned short* __restrict__ hb,
    const unsigned short* __restrict__ wt,
    const int* __restrict__ eidx,
    unsigned short* __restrict__ hpj,
    float* __restrict__ psums)
{
    __shared__ __align__(16) unsigned short ql[128*RSTR];   // 34,816 B q -> vt -> h_proj
    __shared__ __align__(16) unsigned short kl[128*RSTR];   // 34,816 B k -> dense W
    __shared__ __align__(16) short srcl[NODES*DEG];         //  1,856 B
    __shared__ float scf[NODES*DEG];                        //  3,712 B scores -> alpha
    // total 75,200 B -> 2 blocks/CU

    const int b   = blockIdx.x;
    const int g   = b >> 1;
    const int hd  = b & 1;
    const int tid = threadIdx.x;
    const int w    = tid >> 6;
    const int lane = tid & 63;
    const int l15  = lane & 15;
    const int quad = lane >> 4;
    const int wm   = w >> 1;          // 0..3 : 32-row band
    const int wn   = w & 1;           // 0..1 : 64-col half

    #pragma unroll
    for (int p = 0; p < 2; p++) {
        int f = tid + p * 512;
        if (f < NODES * DEG)
            srcl[f] = (short)(eidx[(size_t)g * NODES * DEG + f] - g * NODES);
    }

    // A row pointers (clamped at global end; rows >=116 are don't-care)
    long gr0 = (long)g * NODES + wm * 32 + l15;      if (gr0 >= NN) gr0 = NN - 1;
    long gr1 = (long)g * NODES + wm * 32 + 16 + l15; if (gr1 >= NN) gr1 = NN - 1;
    const unsigned short* ha0 = hb + (size_t)gr0 * HID;
    const unsigned short* ha1 = hb + (size_t)gr1 * HID;
    // B base: + (ch*8+kb)*4096 + j*128 els
    const unsigned short* wchb = wt + (size_t)hd * 4 * 8 * 4096
                                    + (quad * 128 + wn * 64 + l15) * 8;

    #define GEMM_CHUNK(CH, ACC) { \
        _Pragma("unroll") \
        for (int i_ = 0; i_ < 2; i_++) \
            _Pragma("unroll") \
            for (int j_ = 0; j_ < 4; j_++) \
                _Pragma("unroll") \
                for (int r_ = 0; r_ < 4; r_++) ACC[i_][j_][r_] = 0.f; \
        _Pragma("unroll") \
        for (int kb = 0; kb < 8; kb++) { \
            s8v a0 = *(const s8v*)(ha0 + kb * 32 + quad * 8); \
            s8v a1 = *(const s8v*)(ha1 + kb * 32 + quad * 8); \
            _Pragma("unroll") \
            for (int j = 0; j < 4; j++) { \
                s8v bj = *(const s8v*)(wchb + ((CH) * 8 + kb) * 4096 + j * 128); \
                ACC[0][j] = __builtin_amdgcn_mfma_f32_16x16x32_bf16(a0, bj, ACC[0][j], 0, 0, 0); \
                ACC[1][j] = __builtin_amdgcn_mfma_f32_16x16x32_bf16(a1, bj, ACC[1][j], 0, 0, 0); \
            } \
        } }

    f4v acc[2][4];

    // ---- q chunk -> park ql (zero feature dims >=116) ----
    GEMM_CHUNK(0, acc)
    #pragma unroll
    for (int i = 0; i < 2; i++)
        #pragma unroll
        for (int j = 0; j < 4; j++) {
            int col = wn * 64 + j * 16 + l15;
            #pragma unroll
            for (int r = 0; r < 4; r++) {
                int row = wm * 32 + i * 16 + quad * 4 + r;
                ql[row * RSTR + col] = (col < NODES) ? f2bf(acc[i][j][r]) : 0;
            }
        }
    // ---- k chunk -> park kl ----
    GEMM_CHUNK(1, acc)
    #pragma unroll
    for (int i = 0; i < 2; i++)
        #pragma unroll
        for (int j = 0; j < 4; j++) {
            int col = wn * 64 + j * 16 + l15;
            #pragma unroll
            for (int r = 0; r < 4; r++) {
                int row = wm * 32 + i * 16 + quad * 4 + r;
                kl[row * RSTR + col] = (col < NODES) ? f2bf(acc[i][j][r]) : 0;
            }
        }
    __syncthreads();                                  // S1: ql,kl,srcl ready

    // ---- S = Q.K^T (K=128) ----
    f4v sacc[2][4];
    #pragma unroll
    for (int i = 0; i < 2; i++)
        #pragma unroll
        for (int j = 0; j < 4; j++)
            #pragma unroll
            for (int r = 0; r < 4; r++) sacc[i][j][r] = 0.f;
    #pragma unroll
    for (int ks = 0; ks < 4; ks++) {
        s8v a0 = *(const s8v*)(ql + (wm * 32 + l15) * RSTR + ks * 32 + quad * 8);
        s8v a1 = *(const s8v*)(ql + (wm * 32 + 16 + l15) * RSTR + ks * 32 + quad * 8);
        #pragma unroll
        for (int j = 0; j < 4; j++) {
            s8v bj = *(const s8v*)(kl + (wn * 64 + j * 16 + l15) * RSTR + ks * 32 + quad * 8);
            sacc[0][j] = __builtin_amdgcn_mfma_f32_16x16x32_bf16(a0, bj, sacc[0][j], 0, 0, 0);
            sacc[1][j] = __builtin_amdgcn_mfma_f32_16x16x32_bf16(a1, bj, sacc[1][j], 0, 0, 0);
        }
    }
    // selective scatter: exact f32 score per edge
    #pragma unroll
    for (int i = 0; i < 2; i++) {
        #pragma unroll
        for (int r = 0; r < 4; r++) {
            int row = wm * 32 + i * 16 + quad * 4 + r;
            if (row < NODES) {
                s8v sv = *(const s8v*)(srcl + row * DEG);
                #pragma unroll
                for (int j = 0; j < 4; j++) {
                    int col = wn * 64 + j * 16 + l15;
                    #pragma unroll
                    for (int e = 0; e < DEG; e++)
                        if ((int)sv[e] == col)
                            scf[row * DEG + e] = sacc[i][j][r];
                }
            }
        }
    }
    __syncthreads();                                  // S2: scf ready; parks read-done

    // ---- softmax over 8 edges (2 passes of 512) + zero W region ----
    #pragma unroll
    for (int p = 0; p < 2; p++) {
        int f = tid + p * 512;
        if (f < NODES * DEG) {
            float s = scf[f] * 0.09284766908852594f;   // 1/sqrt(116)
            float m = s;
            m = fmaxf(m, __shfl_xor(m, 1));
            m = fmaxf(m, __shfl_xor(m, 2));
            m = fmaxf(m, __shfl_xor(m, 4));
            float e = __expf(s - m);
            float sum = e;
            sum += __shfl_xor(sum, 1);
            sum += __shfl_xor(sum, 2);
            sum += __shfl_xor(sum, 4);
            scf[f] = e / sum;                          // own slot only
        }
    }
    for (int f = tid; f < 128 * RSTR / 8; f += 512)
        *(uint4*)(kl + (size_t)f * 8) = make_uint4(0u, 0u, 0u, 0u);
    __syncthreads();                                  // S3: alpha + zeroed W

    // ---- W-build (waves 0-1); other waves fall through to v-GEMM ----
    if (tid < NODES) {
        #pragma unroll
        for (int j = 0; j < DEG; j++) {
            int sj = srcl[tid * DEG + j];
            bool first = true;
            for (int jj = 0; jj < j; jj++) first = first && (srcl[tid * DEG + jj] != sj);
            if (first) {
                float a = scf[tid * DEG + j];
                for (int jj = j + 1; jj < DEG; jj++)
                    if (srcl[tid * DEG + jj] == sj) a += scf[tid * DEG + jj];
                kl[tid * RSTR + sj] = f2bf(a);
            }
        }
    }
    // ---- v chunk -> park vt[dim][src] into ql-region (global reads only) ----
    GEMM_CHUNK(2, acc)
    #pragma unroll
    for (int i = 0; i < 2; i++)
        #pragma unroll
        for (int j = 0; j < 4; j++) {
            int col = wn * 64 + j * 16 + l15;              // v-dim
            #pragma unroll
            for (int r = 0; r < 4; r++) {
                int row = wm * 32 + i * 16 + quad * 4 + r; // src node
                ql[col * RSTR + row] = (row < NODES) ? f2bf(acc[i][j][r]) : 0;
            }
        }
    __syncthreads();                                  // S4: W + vt ready

    // ---- s chunk (held in regs) ----
    f4v accS[2][4];
    GEMM_CHUNK(3, accS)
    // ---- attn = W @ V (K=128) ----
    #pragma unroll
    for (int i = 0; i < 2; i++)
        #pragma unroll
        for (int j = 0; j < 4; j++)
            #pragma unroll
            for (int r = 0; r < 4; r++) acc[i][j][r] = 0.f;
    #pragma unroll
    for (int ks = 0; ks < 4; ks++) {
        s8v a0 = *(const s8v*)(kl + (wm * 32 + l15) * RSTR + ks * 32 + quad * 8);
        s8v a1 = *(const s8v*)(kl + (wm * 32 + 16 + l15) * RSTR + ks * 32 + quad * 8);
        #pragma unroll
        for (int j = 0; j < 4; j++) {
            s8v bj = *(const s8v*)(ql + (wn * 64 + j * 16 + l15) * RSTR + ks * 32 + quad * 8);
            acc[0][j] = __builtin_amdgcn_mfma_f32_16x16x32_bf16(a0, bj, acc[0][j], 0, 0, 0);
            acc[1][j] = __builtin_amdgcn_mfma_f32_16x16x32_bf16(a1, bj, acc[1][j], 0, 0, 0);
        }
    }
    __syncthreads();                                  // S5: ql (vt) reads done

    // ---- h_proj = attn + s -> park ql (cols>=116 are exact zeros) ----
    #pragma unroll
    for (int i = 0; i < 2; i++)
        #pragma unroll
        for (int j = 0; j < 4; j++) {
            int col = wn * 64 + j * 16 + l15;
            #pragma unroll
            for (int r = 0; r < 4; r++) {
                int row = wm * 32 + i * 16 + quad * 4 + r;
                ql[row * RSTR + col] = f2bf(acc[i][j][r] + accS[i][j][r]);
            }
        }
    __syncthreads();                                  // S6: h_proj parked

    // ---- row partial sums -> psums (2 passes of 512) ----
    #pragma unroll
    for (int p = 0; p < 2; p++) {
        int f = tid + p * 512;
        if (f < NODES * DEG) {
            const int i   = f >> 3;
            const int seg = f & 7;
            float rs = 0.0f;
            #pragma unroll
            for (int t = 0; t < 2; t++) {
                int gi = seg + t * 8;
                if (gi < 15) {
                    const s8v v8 = *(const s8v*)(ql + i * RSTR + gi * 8);
                    #pragma unroll
                    for (int e = 0; e < 8; e++) rs += bf2f((unsigned short)v8[e]);
                }
            }
            rs += __shfl_xor(rs, 1);
            rs += __shfl_xor(rs, 2);
            rs += __shfl_xor(rs, 4);
            if (seg == 0) psums[((size_t)hd * NGRAPH + g) * NODES + i] = rs;
        }
    }
    // ---- hpj[node][232] bf16 (this head's half) ----
    for (int f = tid; f < NODES * 29; f += 512) {
        int r  = f / 29;
        int gi = f - r * 29;
        *(uint2*)(hpj + ((size_t)(g * NODES + r)) * DOUT + hd * DH + gi * 4) =
            *(const uint2*)(ql + r * RSTR + gi * 4);
    }
    #undef GEMM_CHUNK
}

// ---------------------------------------------------------------------------
// K3: per-graph pooling (round-0/5 verified, verbatim layouts).
// ---------------------------------------------------------------------------
__global__ __launch_bounds__(256) void pool_k3(const unsigned short* __restrict__ hp,
                                               const float* __restrict__ psums,
                                               float* __restrict__ out_alpha,
                                               float* __restrict__ out_hw)
{
    __shared__ float ew[NODES];
    __shared__ float alph[NODES];
    __shared__ float red[2];

    const int g   = blockIdx.x;
    const int tid = threadIdx.x;

    if (tid < NODES)
        ew[tid] = (psums[(size_t)g * NODES + tid] +
                   psums[((size_t)NGRAPH + g) * NODES + tid]) * (1.0f / DOUT);
    __syncthreads();
    if (tid < 64) {
        float a = ew[tid];
        float b = (tid + 64 < NODES) ? ew[tid + 64] : -1e30f;
        float mm = fmaxf(a, b);
        #pragma unroll
        for (int off = 32; off > 0; off >>= 1) mm = fmaxf(mm, __shfl_down(mm, off));
        if (tid == 0) red[0] = mm;
    }
    __syncthreads();
    if (tid < NODES) ew[tid] = __expf(ew[tid] - red[0]);
    __syncthreads();
    if (tid < 64) {
        float a = ew[tid] + ((tid + 64 < NODES) ? ew[tid + 64] : 0.0f);
        #pragma unroll
        for (int off = 32; off > 0; off >>= 1) a += __shfl_down(a, off);
        if (tid == 0) red[1] = a;
    }
    __syncthreads();
    if (tid < NODES) {
        float al = ew[tid] / red[1];
        alph[tid] = al;
        out_alpha[(size_t)g * NODES + tid] = al;
    }
    __syncthreads();

    for (int f = tid; f < NODES * 58; f += 256) {   // 58 4-el granules per row
        int r  = f / 58;
        int gi = f - r * 58;
        float al = alph[r];
        uint2 hv = *(const uint2*)(hp + ((size_t)(g * NODES + r)) * DOUT + gi * 4);
        float4 o = make_float4(al * bf2f((unsigned short)(hv.x & 0xFFFF)),
                               al * bf2f((unsigned short)(hv.x >> 16)),
                               al * bf2f((unsigned short)(hv.y & 0xFFFF)),
                               al * bf2f((unsigned short)(hv.y >> 16)));
        *(float4*)(out_hw + ((size_t)(g * NODES + r)) * DOUT + gi * 4) = o;
    }
}

// ===========================================================================
// FALLBACK (ws too small): round-4 verified monolith, unchanged.
// ===========================================================================
__global__ __launch_bounds__(1024, 4) void fused_all(
    const float* __restrict__ h,
    const unsigned short* __restrict__ wt,
    const int* __restrict__ eidx,
    unsigned short* __restrict__ hp,
    float* __restrict__ out_alpha,
    float* __restrict__ out_hw)
{
    __shared__ __align__(16) unsigned short stA[8*4096];
    __shared__ __align__(16) unsigned short ovl[2*128*RSTR];
    __shared__ int   srcl[NODES*DEG];
    __shared__ float scf[NODES*DEG];
    __shared__ float ps[2][NODES];
    __shared__ float red[2];

    unsigned short* const ql = ovl;
    unsigned short* const kl = ovl + 128 * RSTR;

    const int g   = blockIdx.x;
    const int tid = threadIdx.x;
    const int w    = tid >> 6;
    const int lane = tid & 63;
    const int l15  = lane & 15;
    const int quad = lane >> 4;
    const int wm   = w >> 2;
    const int wn   = w & 3;

    if (tid < NODES * DEG)
        srcl[tid] = eidx[(size_t)g * NODES * DEG + tid] - g * NODES;

    {
        const int am = tid >> 3;
        const int q8 = tid & 7;
        long grow = (long)g * NODES + am;
        if (grow >= NN) grow = NN - 1;
        const float* hrow = h + (size_t)grow * HID + q8 * 4;
        const int aoff = ((q8 >> 1) * 128 + am) * 8 + (q8 & 1) * 4;
        float4 a8[8];
        #pragma unroll
        for (int kb = 0; kb < 8; kb++) a8[kb] = *(const float4*)(hrow + kb * 32);
        #pragma unroll
        for (int kb = 0; kb < 8; kb++) {
            unsigned short o[4] = { f2bf(a8[kb].x), f2bf(a8[kb].y),
                                    f2bf(a8[kb].z), f2bf(a8[kb].w) };
            *(uint2*)(stA + kb * 4096 + aoff) = *(const uint2*)o;
        }
    }

    #pragma unroll
    for (int hd = 0; hd < 2; hd++) {
        const size_t wbase = (size_t)hd * 4 * 8 * 4096;

        f4v accq[2][2], acck[2][2], accv[2][2], accs[2][2];
        #pragma unroll
        for (int i = 0; i < 2; i++)
            #pragma unroll
            for (int j = 0; j < 2; j++)
                #pragma unroll
                for (int r = 0; r < 4; r++) {
                    accq[i][j][r] = 0.f; acck[i][j][r] = 0.f;
                    accv[i][j][r] = 0.f; accs[i][j][r] = 0.f;
                }

        #pragma unroll
        for (int j = 0; j < 2; j++) {
            int c = w * 2 + j;
            int ch = c >> 3, sub = c & 7;
            const unsigned short* src = wt + wbase + ((size_t)(ch * 8)) * 4096 + sub * 512;
            GLD_LDS16((const char*)src + lane * 16, (char*)ovl + c * 1024);
        }
        __syncthreads();

        #pragma unroll
        for (int kb = 0; kb < 8; kb++) {
            const unsigned short* curb = ovl + (kb & 1) * 16384;
            unsigned short* nxtb = ovl + ((kb & 1) ^ 1) * 16384;
            if (kb < 7) {
                #pragma unroll
                for (int j = 0; j < 2; j++) {
                    int c = w * 2 + j;
                    int ch = c >> 3, sub = c & 7;
                    const unsigned short* src = wt + wbase + ((size_t)(ch * 8 + kb + 1)) * 4096 + sub * 512;
                    GLD_LDS16((const char*)src + lane * 16, (char*)nxtb + c * 1024);
                }
            }
            const unsigned short* sa = stA + kb * 4096;
            s8v a0 = *(const s8v*)(sa + (quad * 128 + wm * 32 + l15) * 8);
            s8v a1 = *(const s8v*)(sa + (quad * 128 + wm * 32 + 16 + l15) * 8);
            #define CHUNK_MFMA(ACC, CH) { \
                s8v b0 = *(const s8v*)(curb + (CH) * 4096 + (quad * 128 + wn * 32 + l15) * 8); \
                s8v b1 = *(const s8v*)(curb + (CH) * 4096 + (quad * 128 + wn * 32 + 16 + l15) * 8); \
                ACC[0][0] = __builtin_amdgcn_mfma_f32_16x16x32_bf16(a0, b0, ACC[0][0], 0, 0, 0); \
                ACC[0][1] = __builtin_amdgcn_mfma_f32_16x16x32_bf16(a0, b1, ACC[0][1], 0, 0, 0); \
                ACC[1][0] = __builtin_amdgcn_mfma_f32_16x16x32_bf16(a1, b0, ACC[1][0], 0, 0, 0); \
                ACC[1][1] = __builtin_amdgcn_mfma_f32_16x16x32_bf16(a1, b1, ACC[1][1], 0, 0, 0); }
            CHUNK_MFMA(accq, 0)
            CHUNK_MFMA(acck, 1)
            CHUNK_MFMA(accv, 2)
            CHUNK_MFMA(accs, 3)
            #undef CHUNK_MFMA
            __syncthreads();
        }

        #pragma unroll
        for (int i = 0; i < 2; i++) {
            #pragma unroll
            for (int j = 0; j < 2; j++) {
                int col = wn * 32 + j * 16 + l15;
                #pragma unroll
                for (int r = 0; r < 4; r++) {
                    int row = wm * 32 + i * 16 + quad * 4 + r;
                    ql[row * RSTR + col] = (col < NODES) ? f2bf(accq[i][j][r]) : 0;
                    kl[row * RSTR + col] = (col < NODES) ? f2bf(acck[i][j][r]) : 0;
                }
            }
        }
        __syncthreads();

        f4v sacc[2][2];
        #pragma unroll
        for (int i = 0; i < 2; i++)
            #pragma unroll
            for (int j = 0; j < 2; j++)
                #pragma unroll
                for (int r = 0; r < 4; r++) sacc[i][j][r] = 0.f;
        #pragma unroll
        for (int ks = 0; ks < 4; ks++) {
            s8v a0 = *(const s8v*)(ql + (wm * 32 + l15) * RSTR + ks * 32 + quad * 8);
            s8v a1 = *(const s8v*)(ql + (wm * 32 + 16 + l15) * RSTR + ks * 32 + quad * 8);
            s8v b0 = *(const s8v*)(kl + (wn * 32 + l15) * RSTR + ks * 32 + quad * 8);
            s8v b1 = *(const s8v*)(kl + (wn * 32 + 16 + l15) * RSTR + ks * 32 + quad * 8);
            sacc[0][0] = __builtin_amdgcn_mfma_f32_16x16x32_bf16(a0, b0, sacc[0][0], 0, 0, 0);
            sacc[0][1] = __builtin_amdgcn_mfma_f32_16x16x32_bf16(a0, b1, sacc[0][1], 0, 0, 0);
            sacc[1][0] = __builtin_amdgcn_mfma_f32_16x16x32_bf16(a1, b0, sacc[1][0], 0, 0, 0);
            sacc[1][1] = __builtin_amdgcn_mfma_f32_16x16x32_bf16(a1, b1, sacc[1][1], 0, 0, 0);
        }
        #pragma unroll
        for (int i = 0; i < 2; i++) {
            #pragma unroll
            for (int r = 0; r < 4; r++) {
                int row = wm * 32 + i * 16 + quad * 4 + r;
                if (row < NODES) {
                    #pragma unroll
                    for (int j = 0; j < 2; j++) {
                        int col = wn * 32 + j * 16 + l15;
                        #pragma unroll
                        for (int e = 0; e < DEG; e++)
                            if (srcl[row * DEG + e] == col)
                                scf[row * DEG + e] = sacc[i][j][r];
                    }
                }
            }
        }
        __syncthreads();

        for (int f = tid; f < 128 * RSTR / 8; f += 1024)
            *(uint4*)(kl + (size_t)f * 8) = make_uint4(0u, 0u, 0u, 0u);
        #pragma unroll
        for (int i = 0; i < 2; i++) {
            #pragma unroll
            for (int j = 0; j < 2; j++) {
                int col = wn * 32 + j * 16 + l15;
                #pragma unroll
                for (int r = 0; r < 4; r++) {
                    int row = wm * 32 + i * 16 + quad * 4 + r;
                    ql[col * RSTR + row] = (row < NODES) ? f2bf(accv[i][j][r]) : 0;
                }
            }
        }
        __syncthreads();

        if (tid < NODES * DEG) {
            float s = scf[tid] * 0.09284766908852594f;
            float m = s;
            m = fmaxf(m, __shfl_xor(m, 1));
            m = fmaxf(m, __shfl_xor(m, 2));
            m = fmaxf(m, __shfl_xor(m, 4));
            float e = __expf(s - m);
            float sum = e;
            sum += __shfl_xor(sum, 1);
            sum += __shfl_xor(sum, 2);
            sum += __shfl_xor(sum, 4);
            scf[tid] = e / sum;
        }
        __syncthreads();

        if (tid < NODES) {
            #pragma unroll
            for (int j = 0; j < DEG; j++) {
                int sj = srcl[tid * DEG + j];
                bool first = true;
                for (int jj = 0; jj < j; jj++) first = first && (srcl[tid * DEG + jj] != sj);
                if (first) {
                    float a = scf[tid * DEG + j];
                    for (int jj = j + 1; jj < DEG; jj++)
                        if (srcl[tid * DEG + jj] == sj) a += scf[tid * DEG + jj];
                    kl[tid * RSTR + sj] = f2bf(a);
                }
            }
        }
        __syncthreads();

        #pragma unroll
        for (int ks = 0; ks < 4; ks++) {
            s8v a0 = *(const s8v*)(kl + (wm * 32 + l15) * RSTR + ks * 32 + quad * 8);
            s8v a1 = *(const s8v*)(kl + (wm * 32 + 16 + l15) * RSTR + ks * 32 + quad * 8);
            s8v b0 = *(const s8v*)(ql + (wn * 32 + l15) * RSTR + ks * 32 + quad * 8);
            s8v b1 = *(const s8v*)(ql + (wn * 32 + 16 + l15) * RSTR + ks * 32 + quad * 8);
            accs[0][0] = __builtin_amdgcn_mfma_f32_16x16x32_bf16(a0, b0, accs[0][0], 0, 0, 0);
            accs[0][1] = __builtin_amdgcn_mfma_f32_16x16x32_bf16(a0, b1, accs[0][1], 0, 0, 0);
            accs[1][0] = __builtin_amdgcn_mfma_f32_16x16x32_bf16(a1, b0, accs[1][0], 0, 0, 0);
            accs[1][1] = __builtin_amdgcn_mfma_f32_16x16x32_bf16(a1, b1, accs[1][1], 0, 0, 0);
        }
        __syncthreads();

        #pragma unroll
        for (int i = 0; i < 2; i++) {
            #pragma unroll
            for (int j = 0; j < 2; j++) {
                int col = wn * 32 + j * 16 + l15;
                #pragma unroll
                for (int r = 0; r < 4; r++) {
                    int row = wm * 32 + i * 16 + quad * 4 + r;
                    ql[row * RSTR + col] = f2bf(accs[i][j][r]);
                }
            }
        }
        __syncthreads();

        if (tid < NODES * DEG) {
            const int i   = tid >> 3;
            const int seg = tid & 7;
            float rs = 0.0f;
            #pragma unroll
            for (int t = 0; t < 2; t++) {
                int gi = seg + t * 8;
                if (gi < 15) {
                    const s8v v8 = *(const s8v*)(ql + i * RSTR + gi * 8);
                    #pragma unroll
                    for (int e = 0; e < 8; e++) rs += bf2f((unsigned short)v8[e]);
                }
            }
            rs += __shfl_xor(rs, 1);
            rs += __shfl_xor(rs, 2);
            rs += __shfl_xor(rs, 4);
            if (seg == 0) ps[hd][i] = rs;
        }
        if (hd == 0) {
            for (int f = tid; f < NODES * 29; f += 1024) {
                int r  = f / 29;
                int gi = f - r * 29;
                *(uint2*)(hp + ((size_t)g * NODES + r) * 116 + gi * 4) =
                    *(const uint2*)(ql + r * RSTR + gi * 4);
            }
        }
        __syncthreads();
    }

    if (tid < NODES) scf[tid] = (ps[0][tid] + ps[1][tid]) * (1.0f / DOUT);
    __syncthreads();
    if (tid < 64) {
        float a = scf[tid];
        float b = (tid + 64 < NODES) ? scf[tid + 64] : -1e30f;
        float mm = fmaxf(a, b);
        #pragma unroll
        for (int off = 32; off > 0; off >>= 1) mm = fmaxf(mm, __shfl_down(mm, off));
        if (tid == 0) red[0] = mm;
    }
    __syncthreads();
    if (tid < NODES) scf[tid] = __expf(scf[tid] - red[0]);
    __syncthreads();
    if (tid < 64) {
        float a = scf[tid] + ((tid + 64 < NODES) ? scf[tid + 64] : 0.0f);
        #pragma unroll
        for (int off = 32; off > 0; off >>= 1) a += __shfl_down(a, off);
        if (tid == 0) red[1] = a;
    }
    __syncthreads();
    if (tid < NODES) {
        float al = scf[tid] / red[1];
        scf[tid] = al;
        out_alpha[(size_t)g * NODES + tid] = al;
    }
    __syncthreads();
    for (int f = tid; f < NODES * 58; f += 1024) {
        int r  = f / 58;
        int gi = f - r * 58;
        float al = scf[r];
        float4 o;
        if (gi < 29) {
            uint2 hv = *(const uint2*)(hp + ((size_t)g * NODES + r) * 116 + gi * 4);
            o = make_float4(al * bf2f((unsigned short)(hv.x & 0xFFFF)),
                            al * bf2f((unsigned short)(hv.x >> 16)),
                            al * bf2f((unsigned short)(hv.y & 0xFFFF)),
                            al * bf2f((unsigned short)(hv.y >> 16)));
        } else {
            const unsigned short* hv = ql + r * RSTR + (gi - 29) * 4;
            o = make_float4(al * bf2f(hv[0]), al * bf2f(hv[1]),
                            al * bf2f(hv[2]), al * bf2f(hv[3]));
        }
        *(float4*)(out_hw + ((size_t)g * NODES + r) * DOUT + gi * 4) = o;
    }
}

// ---------------------------------------------------------------------------
extern "C" void kernel_launch(void* const* d_in, const int* in_sizes, int n_in,
                              void* d_out, int out_size, void* d_ws, size_t ws_size,
                              hipStream_t stream)
{
    const float* h    = (const float*)d_in[0];
    const int*   eidx = (const int*)d_in[1];   // row 0 = src
    const float* Wq   = (const float*)d_in[3];
    const float* Wk   = (const float*)d_in[4];
    const float* Wv   = (const float*)d_in[5];
    const float* Ws   = (const float*)d_in[6];

    float* out_alpha = (float*)d_out;          // [512][116]
    float* out_hw    = out_alpha + NN;         // [59392][232]

    // Workspace: wt 0.5MB | hb 30.4MB | hpj 27.6MB | psums 0.46MB  (~59MB)
    const size_t WT_ELS  = 262144;
    const size_t HB_ELS  = (size_t)NN * HID;            // 15,204,352
    const size_t HPJ_ELS = (size_t)NN * DOUT;           // 13,778,944
    const size_t NEED = (WT_ELS + HB_ELS + HPJ_ELS) * 2 + (size_t)2 * NGRAPH * NODES * 4;

    unsigned short* wt = (unsigned short*)d_ws;
    prep_w<<<128, 256, 0, stream>>>(Wq, Wk, Wv, Ws, wt);

    if (ws_size >= NEED) {
        unsigned short* hb  = wt + WT_ELS;
        unsigned short* hpj = hb + HB_ELS;
        float*          ps  = (float*)(hpj + HPJ_ELS);
        prep_hb<<<(unsigned)(HB_ELS / (256 * 8)), 256, 0, stream>>>(h, hb);
        k_fused<<<2 * NGRAPH, 512, 0, stream>>>(hb, wt, eidx, hpj, ps);
        pool_k3<<<NGRAPH, 256, 0, stream>>>(hpj, ps, out_alpha, out_hw);
    } else {
        unsigned short* hp = wt + WT_ELS;               // 13.8 MB (head0 only)
        fused_all<<<NGRAPH, 1024, 0, stream>>>(h, wt, eidx, hp, out_alpha, out_hw);
    }
}